// Round 9
// baseline (470.751 us; speedup 1.0000x reference)
//
#include <hip/hip_runtime.h>
#include <math.h>

#define N_NODES 50000
#define E_RAW   1600000
#define TE      (E_RAW + N_NODES)     // 1650000 edges incl. self loops
#define TEP     (TE + 8 * N_NODES)    // CSR padded to 8-aligned rows (upper bound)
#define F_IN    128
#define H1      4
#define F1      128                   // H1*C1
#define F2      64
#define NEG_SLOPE 0.2f
#define EPS_F   1e-16f

// ---- bucket-sort CSR build params (all atomics are LDS-scope) ----
#define NBINS   196                   // coarse buckets: dst >> 8 (50000/256)
#define NBLK_A  128                   // blocks in coarse hist/scatter
#define EPB     ((TE + NBLK_A - 1) / NBLK_A)   // edges per block = 12891
#define SCAN_TOT (NBINS * NBLK_A)     // 25088

__device__ __forceinline__ float lrelu(float v) { return v > 0.f ? v : NEG_SLOPE * v; }

// bf16 round-to-nearest-even pack/unpack (values here are tame: no NaN/Inf)
__device__ __forceinline__ unsigned short f2bf(float f) {
    unsigned u = __float_as_uint(f);
    return (unsigned short)((u + 0x7fffu + ((u >> 16) & 1u)) >> 16);
}
__device__ __forceinline__ float2 bfpair2f(unsigned u) {
    float2 r;
    r.x = __uint_as_float(u << 16);          // low ushort  = even channel
    r.y = __uint_as_float(u & 0xffff0000u);  // high ushort = odd channel
    return r;
}
__device__ __forceinline__ float bf2f(unsigned short s) {
    return __uint_as_float(((unsigned)s) << 16);
}

// ---------------- layer1 matmul + attention coefs ----------------
// 16 nodes/block, 256 threads: c = t&127 (channel), p = t>>7 (node half, 8 nodes).
// xw stored bf16 (gather table); attention coefs fp32-exact from registers.
// #pragma unroll 2: full unroll -> 256 VGPR cliff (round 4).
__global__ __launch_bounds__(256) void k_l1_mm(
    const float* __restrict__ x, const float* __restrict__ W,
    const float* __restrict__ atts, const float* __restrict__ attd,
    unsigned short* __restrict__ xwbf, float* __restrict__ a1s, float* __restrict__ a1d) {
    const int t = threadIdx.x;
    const int c = t & 127;
    const int p = t >> 7;
    const int n0 = blockIdx.x * 16;    // 50000 = 16*3125, no tail
    __shared__ float xs[16][F_IN];
    {
        const float4* src = (const float4*)(x + (size_t)n0 * F_IN);
        float4* dstv = (float4*)&xs[0][0];
        dstv[t] = src[t];
        dstv[t + 256] = src[t + 256];
    }
    __syncthreads();
    float acc[8];
#pragma unroll
    for (int j = 0; j < 8; ++j) acc[j] = 0.f;
    const float* xsp = &xs[p * 8][0];
#pragma unroll 2
    for (int k4 = 0; k4 < F_IN / 4; ++k4) {
        int k = k4 * 4;
        float w0 = W[(k + 0) * F1 + c];
        float w1 = W[(k + 1) * F1 + c];
        float w2 = W[(k + 2) * F1 + c];
        float w3 = W[(k + 3) * F1 + c];
#pragma unroll
        for (int j = 0; j < 8; ++j) {
            float4 xv = ((const float4*)(xsp + j * F_IN))[k4];
            acc[j] = fmaf(xv.x, w0, fmaf(xv.y, w1, fmaf(xv.z, w2, fmaf(xv.w, w3, acc[j]))));
        }
    }
    float ats = atts[c], atd = attd[c];
#pragma unroll
    for (int j = 0; j < 8; ++j) {
        int n = n0 + p * 8 + j;
        xwbf[(size_t)n * F1 + c] = f2bf(acc[j]);
        float ps = acc[j] * ats, pd = acc[j] * atd;
#pragma unroll
        for (int off = 16; off; off >>= 1) {
            ps += __shfl_down(ps, off, 32);
            pd += __shfl_down(pd, off, 32);
        }
        if ((t & 31) == 0) {
            int h = (c >> 5);
            a1s[n * H1 + h] = ps;
            a1d[n * H1 + h] = pd;
        }
    }
}

// ---------------- CSR build step 1: coarse histogram (LDS atomics only) ------
__global__ __launch_bounds__(256) void k_hist_coarse(const int* __restrict__ ei,
                                                     int* __restrict__ cnt) {
    __shared__ int hist[NBINS];
    const int t = threadIdx.x, blk = blockIdx.x;
    for (int i = t; i < NBINS; i += 256) hist[i] = 0;
    __syncthreads();
    const int e0 = blk * EPB, e1 = min(TE, e0 + EPB);
    for (int e = e0 + t; e < e1; e += 256) {
        int d = (e < E_RAW) ? ei[E_RAW + e] : (e - E_RAW);
        atomicAdd(&hist[d >> 8], 1);
    }
    __syncthreads();
    for (int i = t; i < NBINS; i += 256) cnt[i * NBLK_A + blk] = hist[i];
}

// ---------------- CSR build step 2: scan of cnt (bin-major), bucket_start ----
__global__ __launch_bounds__(1024) void k_cscan(int* __restrict__ cnt,
                                                int* __restrict__ bucket_start) {
    __shared__ int wsum[16];
    __shared__ int s_carry;
    const int t = threadIdx.x;
    const int lane = t & 63, w = t >> 6;
    if (t == 0) s_carry = 0;
    __syncthreads();
    for (int base = 0; base < SCAN_TOT; base += 1024) {
        int i = base + t;
        int orig = (i < SCAN_TOT) ? cnt[i] : 0;
        int v = orig;
#pragma unroll
        for (int off = 1; off < 64; off <<= 1) {
            int u = __shfl_up(v, off, 64);
            if (lane >= off) v += u;
        }
        if (lane == 63) wsum[w] = v;
        __syncthreads();
        if (w == 0 && lane < 16) {
            int s = wsum[lane];
#pragma unroll
            for (int off = 1; off < 16; off <<= 1) {
                int u = __shfl_up(s, off, 16);
                if (lane >= off) s += u;
            }
            wsum[lane] = s;
        }
        __syncthreads();
        int incl = v + ((w > 0) ? wsum[w - 1] : 0);
        int excl = incl - orig + s_carry;
        if (i < SCAN_TOT) {
            cnt[i] = excl;
            if ((i & (NBLK_A - 1)) == 0) bucket_start[i / NBLK_A] = excl;
        }
        __syncthreads();
        if (t == 1023) s_carry += wsum[15];
        __syncthreads();
    }
    if (t == 0) bucket_start[NBINS] = TE;
}

// ---------------- CSR build step 3: scatter into coarse buckets --------------
// payload u32 = (dst&255)<<16 | src   (src < 65536)
__global__ __launch_bounds__(256) void k_scatter_coarse(const int* __restrict__ ei,
                                                        const int* __restrict__ cnt,
                                                        unsigned* __restrict__ cbuf) {
    __shared__ int cur[NBINS];
    const int t = threadIdx.x, blk = blockIdx.x;
    for (int i = t; i < NBINS; i += 256) cur[i] = cnt[i * NBLK_A + blk];
    __syncthreads();
    const int e0 = blk * EPB, e1 = min(TE, e0 + EPB);
    for (int e = e0 + t; e < e1; e += 256) {
        int s, d;
        if (e < E_RAW) { s = ei[e]; d = ei[E_RAW + e]; }
        else { s = e - E_RAW; d = s; }
        int pos = atomicAdd(&cur[d >> 8], 1);   // LDS atomic
        unsigned payload = ((unsigned)(d & 255) << 16) | (unsigned)s;
        __builtin_nontemporal_store(payload, &cbuf[pos]);
    }
}

// ---------------- CSR build step 4: fine histogram -> deg --------------------
__global__ __launch_bounds__(256) void k_fine_hist(const unsigned* __restrict__ cbuf,
                                                   const int* __restrict__ bucket_start,
                                                   int* __restrict__ deg) {
    __shared__ int hist[256];
    const int t = threadIdx.x, b = blockIdx.x;
    hist[t] = 0;
    __syncthreads();
    const int i0 = bucket_start[b], i1 = bucket_start[b + 1];
    for (int i = i0 + t; i < i1; i += 256) atomicAdd(&hist[cbuf[i] >> 16], 1);
    __syncthreads();
    const int d = b * 256 + t;
    if (d < N_NODES) deg[d] = hist[t];
}

// ---------------- exclusive scan over 8-PADDED degrees (2-level) --------------
__global__ __launch_bounds__(1024) void k_scan1(const int* __restrict__ deg,
                                                int* __restrict__ incl, int* __restrict__ bsum) {
    int t = threadIdx.x, g = blockIdx.x;
    int idx = g * 1024 + t;
    int v = (idx < N_NODES) ? ((deg[idx] + 7) & ~7) : 0;
    int lane = t & 63, w = t >> 6;
#pragma unroll
    for (int off = 1; off < 64; off <<= 1) {
        int u = __shfl_up(v, off, 64);
        if (lane >= off) v += u;
    }
    __shared__ int ws[16];
    if (lane == 63) ws[w] = v;
    __syncthreads();
    if (w == 0 && lane < 16) {
        int s = ws[lane];
#pragma unroll
        for (int off = 1; off < 16; off <<= 1) {
            int u = __shfl_up(s, off, 16);
            if (lane >= off) s += u;
        }
        ws[lane] = s;
    }
    __syncthreads();
    if (w > 0) v += ws[w - 1];
    if (idx < N_NODES) incl[idx] = v;
    if (t == 1023) bsum[g] = v;
}

__global__ void k_scan2(int* __restrict__ bsum, int nblk) {
    int t = threadIdx.x;
    int v = (t < nblk) ? bsum[t] : 0;
#pragma unroll
    for (int off = 1; off < 64; off <<= 1) {
        int u = __shfl_up(v, off, 64);
        if (t >= off) v += u;
    }
    if (t < nblk) bsum[t] = v;
}

__global__ __launch_bounds__(1024) void k_scan3(const int* __restrict__ incl,
                                                const int* __restrict__ bsum,
                                                int* __restrict__ rowstart) {
    int idx = blockIdx.x * 1024 + threadIdx.x;
    if (idx >= N_NODES) return;
    int off = (blockIdx.x > 0) ? bsum[blockIdx.x - 1] : 0;
    rowstart[idx + 1] = incl[idx] + off;
    if (idx == 0) rowstart[0] = 0;
}

// ---------------- CSR build step 5: per-bucket scatter into csr --------------
// Pad slots are zero-filled later by k_ew1 (unchanged).
__global__ __launch_bounds__(256) void k_build_csr(const unsigned* __restrict__ cbuf,
                                                   const int* __restrict__ bucket_start,
                                                   const int* __restrict__ rowstart,
                                                   int* __restrict__ csr) {
    __shared__ int cur[256];
    const int t = threadIdx.x, b = blockIdx.x;
    const int d = b * 256 + t;
    cur[t] = (d < N_NODES) ? rowstart[d] : 0;
    __syncthreads();
    const int i0 = bucket_start[b], i1 = bucket_start[b + 1];
    for (int i = i0 + t; i < i1; i += 256) {
        unsigned v = cbuf[i];
        int pos = atomicAdd(&cur[v >> 16], 1);   // LDS atomic
        __builtin_nontemporal_store((int)(v & 0xffffu), &csr[pos]);
    }
}

// ---------------- layer1 edge weights + pad zero-fill ----------------
__global__ __launch_bounds__(256) void k_ew1(
    const int* __restrict__ rowstart, int* __restrict__ csr, const int* __restrict__ deg,
    const float* __restrict__ a1s, const float* __restrict__ a1d,
    float* __restrict__ ew1) {
    const int lane = threadIdx.x & 63;
    const int wid = threadIdx.x >> 6;
    const int n = blockIdx.x * 4 + wid;
    if (n >= N_NODES) return;
    const int rs = rowstart[n];
    const int dg = deg[n];
    const int re = rs + dg;
    const int re8 = rs + ((dg + 7) & ~7);
    const float4 ad = ((const float4*)a1d)[n];
    for (int i = rs + lane; i < re8; i += 64) {
        if (i < re) {
            int s = csr[i];
            float4 as = ((const float4*)a1s)[s];
            ew1[0 * TEP + i] = expf(lrelu(as.x + ad.x));
            ew1[1 * TEP + i] = expf(lrelu(as.y + ad.y));
            ew1[2 * TEP + i] = expf(lrelu(as.z + ad.z));
            ew1[3 * TEP + i] = expf(lrelu(as.w + ad.w));
        } else {
            csr[i] = 0;
            ew1[0 * TEP + i] = 0.f;
            ew1[1 * TEP + i] = 0.f;
            ew1[2 * TEP + i] = 0.f;
            ew1[3 * TEP + i] = 0.f;
        }
    }
}

// ---------------- layer1 gather: bf16 rows, 8 edges/iter ----------------
__global__ __launch_bounds__(256) void k_l1_gather(
    const int* __restrict__ rowstart, const int* __restrict__ csr,
    const int* __restrict__ deg, const float* __restrict__ ew1,
    const unsigned short* __restrict__ xwbf, const float* __restrict__ b1,
    float* __restrict__ h1) {
    const int lane = threadIdx.x & 63;
    const int wid = threadIdx.x >> 6;
    const int n = blockIdx.x * 4 + wid;
    if (n >= N_NODES) return;
    const int rs = rowstart[n];
    const int nb8 = (deg[n] + 7) >> 3;
    const int h = lane >> 4;
    const int4* c4 = (const int4*)(csr + rs);
    const float4* w4 = (const float4*)(ew1 + h * TEP + rs);
    const unsigned* xwv = (const unsigned*)xwbf;   // 1 uint = 2 bf16 channels
    float den = 0.f, ax = 0.f, ay = 0.f;
    for (int b = 0; b < nb8; ++b) {
        int4 sA = c4[2 * b], sB = c4[2 * b + 1];
        float4 wA = w4[2 * b], wB = w4[2 * b + 1];
        unsigned u0 = xwv[sA.x * 64 + lane], u1 = xwv[sA.y * 64 + lane];
        unsigned u2 = xwv[sA.z * 64 + lane], u3 = xwv[sA.w * 64 + lane];
        unsigned u4 = xwv[sB.x * 64 + lane], u5 = xwv[sB.y * 64 + lane];
        unsigned u6 = xwv[sB.z * 64 + lane], u7 = xwv[sB.w * 64 + lane];
        float2 v0 = bfpair2f(u0), v1 = bfpair2f(u1), v2 = bfpair2f(u2), v3 = bfpair2f(u3);
        float2 v4 = bfpair2f(u4), v5 = bfpair2f(u5), v6 = bfpair2f(u6), v7 = bfpair2f(u7);
        den += ((wA.x + wA.y) + (wA.z + wA.w)) + ((wB.x + wB.y) + (wB.z + wB.w));
        ax = fmaf(wA.x, v0.x, fmaf(wA.y, v1.x, fmaf(wA.z, v2.x, fmaf(wA.w, v3.x, ax))));
        ay = fmaf(wA.x, v0.y, fmaf(wA.y, v1.y, fmaf(wA.z, v2.y, fmaf(wA.w, v3.y, ay))));
        ax = fmaf(wB.x, v4.x, fmaf(wB.y, v5.x, fmaf(wB.z, v6.x, fmaf(wB.w, v7.x, ax))));
        ay = fmaf(wB.x, v4.y, fmaf(wB.y, v5.y, fmaf(wB.z, v6.y, fmaf(wB.w, v7.y, ay))));
    }
    const float inv = 1.f / (den + EPS_F);
    const int c0 = 2 * lane;
    float o0 = fmaf(ax, inv, b1[c0]);
    float o1 = fmaf(ay, inv, b1[c0 + 1]);
    o0 = o0 > 0.f ? o0 : expm1f(o0);
    o1 = o1 > 0.f ? o1 : expm1f(o1);
    ((float2*)h1)[(size_t)n * 64 + lane] = make_float2(o0, o1);
}

// ---------------- layer2 matmul + attention coefs ----------------
// 16 nodes/block, 256 threads: c = t&63, p = t>>6 (4 nodes each). xw2 bf16.
__global__ __launch_bounds__(256) void k_l2_mm(
    const float* __restrict__ h1, const float* __restrict__ W,
    const float* __restrict__ atts, const float* __restrict__ attd,
    unsigned short* __restrict__ xwbf, float* __restrict__ a2s, float* __restrict__ a2d) {
    const int t = threadIdx.x;
    const int c = t & 63;
    const int p = t >> 6;
    const int n0 = blockIdx.x * 16;    // 3125 blocks
    __shared__ float xs[16][F1];
    {
        const float4* src = (const float4*)(h1 + (size_t)n0 * F1);
        float4* dstv = (float4*)&xs[0][0];
        dstv[t] = src[t];
        dstv[t + 256] = src[t + 256];
    }
    __syncthreads();
    float acc[4];
#pragma unroll
    for (int j = 0; j < 4; ++j) acc[j] = 0.f;
    const float* xsp = &xs[p * 4][0];
#pragma unroll 2
    for (int k4 = 0; k4 < F1 / 4; ++k4) {
        int k = k4 * 4;
        float w0 = W[(k + 0) * F2 + c];
        float w1 = W[(k + 1) * F2 + c];
        float w2 = W[(k + 2) * F2 + c];
        float w3 = W[(k + 3) * F2 + c];
#pragma unroll
        for (int j = 0; j < 4; ++j) {
            float4 xv = ((const float4*)(xsp + j * F1))[k4];
            acc[j] = fmaf(xv.x, w0, fmaf(xv.y, w1, fmaf(xv.z, w2, fmaf(xv.w, w3, acc[j]))));
        }
    }
    float ats = atts[c], atd = attd[c];
#pragma unroll
    for (int j = 0; j < 4; ++j) {
        int n = n0 + p * 4 + j;
        xwbf[(size_t)n * F2 + c] = f2bf(acc[j]);
        float ps = acc[j] * ats, pd = acc[j] * atd;
#pragma unroll
        for (int off = 32; off; off >>= 1) {
            ps += __shfl_down(ps, off, 64);
            pd += __shfl_down(pd, off, 64);
        }
        if (c == 0) { a2s[n] = ps; a2d[n] = pd; }
    }
}

// ---------------- layer2 edge weights ----------------
__global__ __launch_bounds__(256) void k_ew2(
    const int* __restrict__ rowstart, const int* __restrict__ csr,
    const int* __restrict__ deg,
    const float* __restrict__ a2s, const float* __restrict__ a2d,
    float* __restrict__ ew2) {
    const int lane = threadIdx.x & 63;
    const int wid = threadIdx.x >> 6;
    const int n = blockIdx.x * 4 + wid;
    if (n >= N_NODES) return;
    const int rs = rowstart[n];
    const int dg = deg[n];
    const int re = rs + dg;
    const int re8 = rs + ((dg + 7) & ~7);
    const float adv = a2d[n];
    for (int i = rs + lane; i < re8; i += 64) {
        if (i < re) {
            int s = csr[i];
            ew2[i] = expf(lrelu(a2s[s] + adv));
        } else {
            ew2[i] = 0.f;
        }
    }
}

// ---------------- layer2 gather: bf16 rows, 8 edges/iter ----------------
__global__ __launch_bounds__(256) void k_l2_gather(
    const int* __restrict__ rowstart, const int* __restrict__ csr,
    const int* __restrict__ deg, const float* __restrict__ ew2,
    const unsigned short* __restrict__ xwbf, float* __restrict__ h2) {
    const int lane = threadIdx.x & 63;
    const int wid = threadIdx.x >> 6;
    const int n = blockIdx.x * 4 + wid;
    if (n >= N_NODES) return;
    const int rs = rowstart[n];
    const int nb8 = (deg[n] + 7) >> 3;
    const int4* c4 = (const int4*)(csr + rs);
    const float4* w4 = (const float4*)(ew2 + rs);
    float den = 0.f, acc = 0.f;
    for (int b = 0; b < nb8; ++b) {
        int4 sA = c4[2 * b], sB = c4[2 * b + 1];
        float4 wA = w4[2 * b], wB = w4[2 * b + 1];
        float v0 = bf2f(xwbf[(size_t)sA.x * F2 + lane]);
        float v1 = bf2f(xwbf[(size_t)sA.y * F2 + lane]);
        float v2 = bf2f(xwbf[(size_t)sA.z * F2 + lane]);
        float v3 = bf2f(xwbf[(size_t)sA.w * F2 + lane]);
        float v4 = bf2f(xwbf[(size_t)sB.x * F2 + lane]);
        float v5 = bf2f(xwbf[(size_t)sB.y * F2 + lane]);
        float v6 = bf2f(xwbf[(size_t)sB.z * F2 + lane]);
        float v7 = bf2f(xwbf[(size_t)sB.w * F2 + lane]);
        den += ((wA.x + wA.y) + (wA.z + wA.w)) + ((wB.x + wB.y) + (wB.z + wB.w));
        acc = fmaf(wA.x, v0, fmaf(wA.y, v1, fmaf(wA.z, v2, fmaf(wA.w, v3, acc))));
        acc = fmaf(wB.x, v4, fmaf(wB.y, v5, fmaf(wB.z, v6, fmaf(wB.w, v7, acc))));
    }
    h2[(size_t)n * F2 + lane] = acc / (den + EPS_F);
}

// ---------------- mean over nodes (fp64 accum) ----------------
#define MEAN_BLOCKS 256
__global__ __launch_bounds__(256) void k_mean(const float* __restrict__ h2,
                                              double* __restrict__ accum) {
    const int t = threadIdx.x;
    const int c = t & 63;
    double acc = 0.0;
    const size_t total = (size_t)N_NODES * F2;
    for (size_t idx = (size_t)blockIdx.x * 256 + t; idx < total; idx += (size_t)MEAN_BLOCKS * 256)
        acc += (double)h2[idx];
    __shared__ double red[256];
    red[t] = acc;
    __syncthreads();
    if (t < 64) {
        double v = red[t] + red[t + 64] + red[t + 128] + red[t + 192];
        atomicAdd(&accum[c], v);
    }
}

__global__ void k_final(const double* __restrict__ accum, const float* __restrict__ b2,
                        float* __restrict__ out) {
    int t = threadIdx.x;
    if (t < F2) out[t] = (float)(accum[t] * (1.0 / (double)N_NODES)) + b2[t];
}

// ---------------- launch ----------------
extern "C" void kernel_launch(void* const* d_in, const int* in_sizes, int n_in,
                              void* d_out, int out_size, void* d_ws, size_t ws_size,
                              hipStream_t stream) {
    (void)in_sizes; (void)n_in; (void)out_size; (void)ws_size;
    const float* x   = (const float*)d_in[0];
    const int*   ei  = (const int*)d_in[1];
    const float* W1  = (const float*)d_in[2];
    const float* as1 = (const float*)d_in[3];
    const float* ad1 = (const float*)d_in[4];
    const float* b1  = (const float*)d_in[5];
    const float* W2  = (const float*)d_in[6];
    const float* as2 = (const float*)d_in[7];
    const float* ad2 = (const float*)d_in[8];
    const float* b2  = (const float*)d_in[9];
    float* out = (float*)d_out;

    char* ws = (char*)d_ws;
    size_t off = 0;
    auto alloc = [&](size_t bytes) -> void* {
        void* p = ws + off;
        off += (bytes + 255) & ~(size_t)255;
        return p;
    };
    unsigned short* xw1bf = (unsigned short*)alloc((size_t)N_NODES * F1 * 2);
    float* h1       = (float*)alloc((size_t)N_NODES * F1 * 4);
    unsigned short* xw2bf = (unsigned short*)alloc((size_t)N_NODES * F2 * 2);
    float* h2       = (float*)alloc((size_t)N_NODES * F2 * 4);
    float* ew1      = (float*)alloc((size_t)H1 * TEP * 4);
    float* ew2      = (float*)alloc((size_t)TEP * 4);
    float* a1s      = (float*)alloc((size_t)N_NODES * H1 * 4);
    float* a1d      = (float*)alloc((size_t)N_NODES * H1 * 4);
    float* a2s      = (float*)alloc((size_t)N_NODES * 4);
    float* a2d      = (float*)alloc((size_t)N_NODES * 4);
    int*   deg      = (int*)alloc((size_t)N_NODES * 4);
    unsigned* cbuf  = (unsigned*)alloc((size_t)TE * 4);
    int*   cnt      = (int*)alloc((size_t)SCAN_TOT * 4);
    int*   bstart   = (int*)alloc((size_t)(NBINS + 1) * 4);
    int*   rowstart = (int*)alloc((size_t)(N_NODES + 1) * 4);
    int*   csr      = (int*)alloc((size_t)TEP * 4);
    int*   incl     = (int*)alloc((size_t)N_NODES * 4);
    int*   bsum     = (int*)alloc(64 * 4);
    double* accum   = (double*)alloc(F2 * 8);

    const int nscan = (N_NODES + 1023) / 1024;  // 49
    const int nwave4 = (N_NODES + 3) / 4;       // 12500

    hipMemsetAsync(accum, 0, F2 * 8, stream);
    k_l1_mm<<<N_NODES / 16, 256, 0, stream>>>(x, W1, as1, ad1, xw1bf, a1s, a1d);
    k_hist_coarse<<<NBLK_A, 256, 0, stream>>>(ei, cnt);
    k_cscan<<<1, 1024, 0, stream>>>(cnt, bstart);
    k_scatter_coarse<<<NBLK_A, 256, 0, stream>>>(ei, cnt, cbuf);
    k_fine_hist<<<NBINS, 256, 0, stream>>>(cbuf, bstart, deg);
    k_scan1<<<nscan, 1024, 0, stream>>>(deg, incl, bsum);
    k_scan2<<<1, 64, 0, stream>>>(bsum, nscan);
    k_scan3<<<nscan, 1024, 0, stream>>>(incl, bsum, rowstart);
    k_build_csr<<<NBINS, 256, 0, stream>>>(cbuf, bstart, rowstart, csr);
    k_ew1<<<nwave4, 256, 0, stream>>>(rowstart, csr, deg, a1s, a1d, ew1);
    k_l1_gather<<<nwave4, 256, 0, stream>>>(rowstart, csr, deg, ew1, xw1bf, b1, h1);
    k_l2_mm<<<N_NODES / 16, 256, 0, stream>>>(h1, W2, as2, ad2, xw2bf, a2s, a2d);
    k_ew2<<<nwave4, 256, 0, stream>>>(rowstart, csr, deg, a2s, a2d, ew2);
    k_l2_gather<<<nwave4, 256, 0, stream>>>(rowstart, csr, deg, ew2, xw2bf, h2);
    k_mean<<<MEAN_BLOCKS, 256, 0, stream>>>(h2, accum);
    k_final<<<1, 64, 0, stream>>>(accum, b2, out);
}

// Round 10
// 399.607 us; speedup vs baseline: 1.1780x; 1.1780x over previous
//
#include <hip/hip_runtime.h>
#include <math.h>

#define N_NODES 50000
#define E_RAW   1600000
#define TE      (E_RAW + N_NODES)     // 1650000 edges incl. self loops
#define TEP     (TE + 8 * N_NODES)    // CSR padded to 8-aligned rows (upper bound)
#define F_IN    128
#define H1      4
#define F1      128                   // H1*C1
#define F2      64
#define NEG_SLOPE 0.2f
#define EPS_F   1e-16f

// ---- bucket-sort CSR build params (all atomics are LDS-scope) ----
#define NBINS   196                   // coarse buckets: dst >> 8 (50000/256)
#define NBLK_A  128                   // blocks in coarse hist/scatter
#define EPB     ((TE + NBLK_A - 1) / NBLK_A)   // edges per block = 12891
#define SCAN_TOT (NBINS * NBLK_A)     // 25088

__device__ __forceinline__ float lrelu(float v) { return v > 0.f ? v : NEG_SLOPE * v; }

// bf16 round-to-nearest-even pack/unpack (values here are tame: no NaN/Inf)
__device__ __forceinline__ unsigned short f2bf(float f) {
    unsigned u = __float_as_uint(f);
    return (unsigned short)((u + 0x7fffu + ((u >> 16) & 1u)) >> 16);
}
__device__ __forceinline__ float2 bfpair2f(unsigned u) {
    float2 r;
    r.x = __uint_as_float(u << 16);          // low ushort  = even channel
    r.y = __uint_as_float(u & 0xffff0000u);  // high ushort = odd channel
    return r;
}
__device__ __forceinline__ float bf2f(unsigned short s) {
    return __uint_as_float(((unsigned)s) << 16);
}

// ---------------- layer1 matmul + attention coefs ----------------
// 16 nodes/block, 256 threads: c = t&127 (channel), p = t>>7 (node half, 8 nodes).
// xw stored bf16 (gather table); attention coefs fp32-exact from registers.
// #pragma unroll 2: full unroll -> 256 VGPR cliff (round 4).
__global__ __launch_bounds__(256) void k_l1_mm(
    const float* __restrict__ x, const float* __restrict__ W,
    const float* __restrict__ atts, const float* __restrict__ attd,
    unsigned short* __restrict__ xwbf, float* __restrict__ a1s, float* __restrict__ a1d) {
    const int t = threadIdx.x;
    const int c = t & 127;
    const int p = t >> 7;
    const int n0 = blockIdx.x * 16;    // 50000 = 16*3125, no tail
    __shared__ float xs[16][F_IN];
    {
        const float4* src = (const float4*)(x + (size_t)n0 * F_IN);
        float4* dstv = (float4*)&xs[0][0];
        dstv[t] = src[t];
        dstv[t + 256] = src[t + 256];
    }
    __syncthreads();
    float acc[8];
#pragma unroll
    for (int j = 0; j < 8; ++j) acc[j] = 0.f;
    const float* xsp = &xs[p * 8][0];
#pragma unroll 2
    for (int k4 = 0; k4 < F_IN / 4; ++k4) {
        int k = k4 * 4;
        float w0 = W[(k + 0) * F1 + c];
        float w1 = W[(k + 1) * F1 + c];
        float w2 = W[(k + 2) * F1 + c];
        float w3 = W[(k + 3) * F1 + c];
#pragma unroll
        for (int j = 0; j < 8; ++j) {
            float4 xv = ((const float4*)(xsp + j * F_IN))[k4];
            acc[j] = fmaf(xv.x, w0, fmaf(xv.y, w1, fmaf(xv.z, w2, fmaf(xv.w, w3, acc[j]))));
        }
    }
    float ats = atts[c], atd = attd[c];
#pragma unroll
    for (int j = 0; j < 8; ++j) {
        int n = n0 + p * 8 + j;
        xwbf[(size_t)n * F1 + c] = f2bf(acc[j]);
        float ps = acc[j] * ats, pd = acc[j] * atd;
#pragma unroll
        for (int off = 16; off; off >>= 1) {
            ps += __shfl_down(ps, off, 32);
            pd += __shfl_down(pd, off, 32);
        }
        if ((t & 31) == 0) {
            int h = (c >> 5);
            a1s[n * H1 + h] = ps;
            a1d[n * H1 + h] = pd;
        }
    }
}

// ---------------- CSR build step 1: coarse histogram (LDS atomics only) ------
__global__ __launch_bounds__(256) void k_hist_coarse(const int* __restrict__ ei,
                                                     int* __restrict__ cnt) {
    __shared__ int hist[NBINS];
    const int t = threadIdx.x, blk = blockIdx.x;
    for (int i = t; i < NBINS; i += 256) hist[i] = 0;
    __syncthreads();
    const int e0 = blk * EPB, e1 = min(TE, e0 + EPB);
    for (int e = e0 + t; e < e1; e += 256) {
        int d = (e < E_RAW) ? ei[E_RAW + e] : (e - E_RAW);
        atomicAdd(&hist[d >> 8], 1);
    }
    __syncthreads();
    for (int i = t; i < NBINS; i += 256) cnt[i * NBLK_A + blk] = hist[i];
}

// ---------------- CSR build step 2: scan of cnt (bin-major), bucket_start ----
__global__ __launch_bounds__(1024) void k_cscan(int* __restrict__ cnt,
                                                int* __restrict__ bucket_start) {
    __shared__ int wsum[16];
    __shared__ int s_carry;
    const int t = threadIdx.x;
    const int lane = t & 63, w = t >> 6;
    if (t == 0) s_carry = 0;
    __syncthreads();
    for (int base = 0; base < SCAN_TOT; base += 1024) {
        int i = base + t;
        int orig = (i < SCAN_TOT) ? cnt[i] : 0;
        int v = orig;
#pragma unroll
        for (int off = 1; off < 64; off <<= 1) {
            int u = __shfl_up(v, off, 64);
            if (lane >= off) v += u;
        }
        if (lane == 63) wsum[w] = v;
        __syncthreads();
        if (w == 0 && lane < 16) {
            int s = wsum[lane];
#pragma unroll
            for (int off = 1; off < 16; off <<= 1) {
                int u = __shfl_up(s, off, 16);
                if (lane >= off) s += u;
            }
            wsum[lane] = s;
        }
        __syncthreads();
        int incl = v + ((w > 0) ? wsum[w - 1] : 0);
        int excl = incl - orig + s_carry;
        if (i < SCAN_TOT) {
            cnt[i] = excl;
            if ((i & (NBLK_A - 1)) == 0) bucket_start[i / NBLK_A] = excl;
        }
        __syncthreads();
        if (t == 1023) s_carry += wsum[15];
        __syncthreads();
    }
    if (t == 0) bucket_start[NBINS] = TE;
}

// ---------------- CSR build step 3: scatter into coarse buckets --------------
// payload u32 = (dst&255)<<16 | src   (src < 65536)
// Plain store (NOT nontemporal): per-block bucket regions are contiguous
// advancing streams -> L2 write-back coalesces 4B stores into full lines.
// nt store bypassed L2 and cost ~64B HBM traffic per 4B store (round 9).
__global__ __launch_bounds__(256) void k_scatter_coarse(const int* __restrict__ ei,
                                                        const int* __restrict__ cnt,
                                                        unsigned* __restrict__ cbuf) {
    __shared__ int cur[NBINS];
    const int t = threadIdx.x, blk = blockIdx.x;
    for (int i = t; i < NBINS; i += 256) cur[i] = cnt[i * NBLK_A + blk];
    __syncthreads();
    const int e0 = blk * EPB, e1 = min(TE, e0 + EPB);
    for (int e = e0 + t; e < e1; e += 256) {
        int s, d;
        if (e < E_RAW) { s = ei[e]; d = ei[E_RAW + e]; }
        else { s = e - E_RAW; d = s; }
        int pos = atomicAdd(&cur[d >> 8], 1);   // LDS atomic
        cbuf[pos] = ((unsigned)(d & 255) << 16) | (unsigned)s;
    }
}

// ---------------- CSR build step 4: fine histogram -> deg --------------------
__global__ __launch_bounds__(256) void k_fine_hist(const unsigned* __restrict__ cbuf,
                                                   const int* __restrict__ bucket_start,
                                                   int* __restrict__ deg) {
    __shared__ int hist[256];
    const int t = threadIdx.x, b = blockIdx.x;
    hist[t] = 0;
    __syncthreads();
    const int i0 = bucket_start[b], i1 = bucket_start[b + 1];
    for (int i = i0 + t; i < i1; i += 256) atomicAdd(&hist[cbuf[i] >> 16], 1);
    __syncthreads();
    const int d = b * 256 + t;
    if (d < N_NODES) deg[d] = hist[t];
}

// ---------------- exclusive scan over 8-PADDED degrees (2-level) --------------
__global__ __launch_bounds__(1024) void k_scan1(const int* __restrict__ deg,
                                                int* __restrict__ incl, int* __restrict__ bsum) {
    int t = threadIdx.x, g = blockIdx.x;
    int idx = g * 1024 + t;
    int v = (idx < N_NODES) ? ((deg[idx] + 7) & ~7) : 0;
    int lane = t & 63, w = t >> 6;
#pragma unroll
    for (int off = 1; off < 64; off <<= 1) {
        int u = __shfl_up(v, off, 64);
        if (lane >= off) v += u;
    }
    __shared__ int ws[16];
    if (lane == 63) ws[w] = v;
    __syncthreads();
    if (w == 0 && lane < 16) {
        int s = ws[lane];
#pragma unroll
        for (int off = 1; off < 16; off <<= 1) {
            int u = __shfl_up(s, off, 16);
            if (lane >= off) s += u;
        }
        ws[lane] = s;
    }
    __syncthreads();
    if (w > 0) v += ws[w - 1];
    if (idx < N_NODES) incl[idx] = v;
    if (t == 1023) bsum[g] = v;
}

__global__ void k_scan2(int* __restrict__ bsum, int nblk) {
    int t = threadIdx.x;
    int v = (t < nblk) ? bsum[t] : 0;
#pragma unroll
    for (int off = 1; off < 64; off <<= 1) {
        int u = __shfl_up(v, off, 64);
        if (t >= off) v += u;
    }
    if (t < nblk) bsum[t] = v;
}

__global__ __launch_bounds__(1024) void k_scan3(const int* __restrict__ incl,
                                                const int* __restrict__ bsum,
                                                int* __restrict__ rowstart) {
    int idx = blockIdx.x * 1024 + threadIdx.x;
    if (idx >= N_NODES) return;
    int off = (blockIdx.x > 0) ? bsum[blockIdx.x - 1] : 0;
    rowstart[idx + 1] = incl[idx] + off;
    if (idx == 0) rowstart[0] = 0;
}

// ---------------- CSR build step 5: per-bucket scatter into csr --------------
// Plain store: each bucket's csr range is ~40KB, L2-resident -> write-back
// coalesces. Pad slots are zero-filled later by k_ew1 (unchanged).
__global__ __launch_bounds__(256) void k_build_csr(const unsigned* __restrict__ cbuf,
                                                   const int* __restrict__ bucket_start,
                                                   const int* __restrict__ rowstart,
                                                   int* __restrict__ csr) {
    __shared__ int cur[256];
    const int t = threadIdx.x, b = blockIdx.x;
    const int d = b * 256 + t;
    cur[t] = (d < N_NODES) ? rowstart[d] : 0;
    __syncthreads();
    const int i0 = bucket_start[b], i1 = bucket_start[b + 1];
    for (int i = i0 + t; i < i1; i += 256) {
        unsigned v = cbuf[i];
        int pos = atomicAdd(&cur[v >> 16], 1);   // LDS atomic
        csr[pos] = (int)(v & 0xffffu);
    }
}

// ---------------- layer1 edge weights + pad zero-fill ----------------
__global__ __launch_bounds__(256) void k_ew1(
    const int* __restrict__ rowstart, int* __restrict__ csr, const int* __restrict__ deg,
    const float* __restrict__ a1s, const float* __restrict__ a1d,
    float* __restrict__ ew1) {
    const int lane = threadIdx.x & 63;
    const int wid = threadIdx.x >> 6;
    const int n = blockIdx.x * 4 + wid;
    if (n >= N_NODES) return;
    const int rs = rowstart[n];
    const int dg = deg[n];
    const int re = rs + dg;
    const int re8 = rs + ((dg + 7) & ~7);
    const float4 ad = ((const float4*)a1d)[n];
    for (int i = rs + lane; i < re8; i += 64) {
        if (i < re) {
            int s = csr[i];
            float4 as = ((const float4*)a1s)[s];
            ew1[0 * TEP + i] = expf(lrelu(as.x + ad.x));
            ew1[1 * TEP + i] = expf(lrelu(as.y + ad.y));
            ew1[2 * TEP + i] = expf(lrelu(as.z + ad.z));
            ew1[3 * TEP + i] = expf(lrelu(as.w + ad.w));
        } else {
            csr[i] = 0;
            ew1[0 * TEP + i] = 0.f;
            ew1[1 * TEP + i] = 0.f;
            ew1[2 * TEP + i] = 0.f;
            ew1[3 * TEP + i] = 0.f;
        }
    }
}

// ---------------- layer1 gather: bf16 rows, 8 edges/iter ----------------
__global__ __launch_bounds__(256) void k_l1_gather(
    const int* __restrict__ rowstart, const int* __restrict__ csr,
    const int* __restrict__ deg, const float* __restrict__ ew1,
    const unsigned short* __restrict__ xwbf, const float* __restrict__ b1,
    float* __restrict__ h1) {
    const int lane = threadIdx.x & 63;
    const int wid = threadIdx.x >> 6;
    const int n = blockIdx.x * 4 + wid;
    if (n >= N_NODES) return;
    const int rs = rowstart[n];
    const int nb8 = (deg[n] + 7) >> 3;
    const int h = lane >> 4;
    const int4* c4 = (const int4*)(csr + rs);
    const float4* w4 = (const float4*)(ew1 + h * TEP + rs);
    const unsigned* xwv = (const unsigned*)xwbf;   // 1 uint = 2 bf16 channels
    float den = 0.f, ax = 0.f, ay = 0.f;
    for (int b = 0; b < nb8; ++b) {
        int4 sA = c4[2 * b], sB = c4[2 * b + 1];
        float4 wA = w4[2 * b], wB = w4[2 * b + 1];
        unsigned u0 = xwv[sA.x * 64 + lane], u1 = xwv[sA.y * 64 + lane];
        unsigned u2 = xwv[sA.z * 64 + lane], u3 = xwv[sA.w * 64 + lane];
        unsigned u4 = xwv[sB.x * 64 + lane], u5 = xwv[sB.y * 64 + lane];
        unsigned u6 = xwv[sB.z * 64 + lane], u7 = xwv[sB.w * 64 + lane];
        float2 v0 = bfpair2f(u0), v1 = bfpair2f(u1), v2 = bfpair2f(u2), v3 = bfpair2f(u3);
        float2 v4 = bfpair2f(u4), v5 = bfpair2f(u5), v6 = bfpair2f(u6), v7 = bfpair2f(u7);
        den += ((wA.x + wA.y) + (wA.z + wA.w)) + ((wB.x + wB.y) + (wB.z + wB.w));
        ax = fmaf(wA.x, v0.x, fmaf(wA.y, v1.x, fmaf(wA.z, v2.x, fmaf(wA.w, v3.x, ax))));
        ay = fmaf(wA.x, v0.y, fmaf(wA.y, v1.y, fmaf(wA.z, v2.y, fmaf(wA.w, v3.y, ay))));
        ax = fmaf(wB.x, v4.x, fmaf(wB.y, v5.x, fmaf(wB.z, v6.x, fmaf(wB.w, v7.x, ax))));
        ay = fmaf(wB.x, v4.y, fmaf(wB.y, v5.y, fmaf(wB.z, v6.y, fmaf(wB.w, v7.y, ay))));
    }
    const float inv = 1.f / (den + EPS_F);
    const int c0 = 2 * lane;
    float o0 = fmaf(ax, inv, b1[c0]);
    float o1 = fmaf(ay, inv, b1[c0 + 1]);
    o0 = o0 > 0.f ? o0 : expm1f(o0);
    o1 = o1 > 0.f ? o1 : expm1f(o1);
    ((float2*)h1)[(size_t)n * 64 + lane] = make_float2(o0, o1);
}

// ---------------- layer2 matmul + attention coefs ----------------
// 16 nodes/block, 256 threads: c = t&63, p = t>>6 (4 nodes each). xw2 bf16.
__global__ __launch_bounds__(256) void k_l2_mm(
    const float* __restrict__ h1, const float* __restrict__ W,
    const float* __restrict__ atts, const float* __restrict__ attd,
    unsigned short* __restrict__ xwbf, float* __restrict__ a2s, float* __restrict__ a2d) {
    const int t = threadIdx.x;
    const int c = t & 63;
    const int p = t >> 6;
    const int n0 = blockIdx.x * 16;    // 3125 blocks
    __shared__ float xs[16][F1];
    {
        const float4* src = (const float4*)(h1 + (size_t)n0 * F1);
        float4* dstv = (float4*)&xs[0][0];
        dstv[t] = src[t];
        dstv[t + 256] = src[t + 256];
    }
    __syncthreads();
    float acc[4];
#pragma unroll
    for (int j = 0; j < 4; ++j) acc[j] = 0.f;
    const float* xsp = &xs[p * 4][0];
#pragma unroll 2
    for (int k4 = 0; k4 < F1 / 4; ++k4) {
        int k = k4 * 4;
        float w0 = W[(k + 0) * F2 + c];
        float w1 = W[(k + 1) * F2 + c];
        float w2 = W[(k + 2) * F2 + c];
        float w3 = W[(k + 3) * F2 + c];
#pragma unroll
        for (int j = 0; j < 4; ++j) {
            float4 xv = ((const float4*)(xsp + j * F1))[k4];
            acc[j] = fmaf(xv.x, w0, fmaf(xv.y, w1, fmaf(xv.z, w2, fmaf(xv.w, w3, acc[j]))));
        }
    }
    float ats = atts[c], atd = attd[c];
#pragma unroll
    for (int j = 0; j < 4; ++j) {
        int n = n0 + p * 4 + j;
        xwbf[(size_t)n * F2 + c] = f2bf(acc[j]);
        float ps = acc[j] * ats, pd = acc[j] * atd;
#pragma unroll
        for (int off = 32; off; off >>= 1) {
            ps += __shfl_down(ps, off, 64);
            pd += __shfl_down(pd, off, 64);
        }
        if (c == 0) { a2s[n] = ps; a2d[n] = pd; }
    }
}

// ---------------- layer2 edge weights ----------------
__global__ __launch_bounds__(256) void k_ew2(
    const int* __restrict__ rowstart, const int* __restrict__ csr,
    const int* __restrict__ deg,
    const float* __restrict__ a2s, const float* __restrict__ a2d,
    float* __restrict__ ew2) {
    const int lane = threadIdx.x & 63;
    const int wid = threadIdx.x >> 6;
    const int n = blockIdx.x * 4 + wid;
    if (n >= N_NODES) return;
    const int rs = rowstart[n];
    const int dg = deg[n];
    const int re = rs + dg;
    const int re8 = rs + ((dg + 7) & ~7);
    const float adv = a2d[n];
    for (int i = rs + lane; i < re8; i += 64) {
        if (i < re) {
            int s = csr[i];
            ew2[i] = expf(lrelu(a2s[s] + adv));
        } else {
            ew2[i] = 0.f;
        }
    }
}

// ---------------- layer2 gather: bf16 rows, 8 edges/iter ----------------
__global__ __launch_bounds__(256) void k_l2_gather(
    const int* __restrict__ rowstart, const int* __restrict__ csr,
    const int* __restrict__ deg, const float* __restrict__ ew2,
    const unsigned short* __restrict__ xwbf, float* __restrict__ h2) {
    const int lane = threadIdx.x & 63;
    const int wid = threadIdx.x >> 6;
    const int n = blockIdx.x * 4 + wid;
    if (n >= N_NODES) return;
    const int rs = rowstart[n];
    const int nb8 = (deg[n] + 7) >> 3;
    const int4* c4 = (const int4*)(csr + rs);
    const float4* w4 = (const float4*)(ew2 + rs);
    float den = 0.f, acc = 0.f;
    for (int b = 0; b < nb8; ++b) {
        int4 sA = c4[2 * b], sB = c4[2 * b + 1];
        float4 wA = w4[2 * b], wB = w4[2 * b + 1];
        float v0 = bf2f(xwbf[(size_t)sA.x * F2 + lane]);
        float v1 = bf2f(xwbf[(size_t)sA.y * F2 + lane]);
        float v2 = bf2f(xwbf[(size_t)sA.z * F2 + lane]);
        float v3 = bf2f(xwbf[(size_t)sA.w * F2 + lane]);
        float v4 = bf2f(xwbf[(size_t)sB.x * F2 + lane]);
        float v5 = bf2f(xwbf[(size_t)sB.y * F2 + lane]);
        float v6 = bf2f(xwbf[(size_t)sB.z * F2 + lane]);
        float v7 = bf2f(xwbf[(size_t)sB.w * F2 + lane]);
        den += ((wA.x + wA.y) + (wA.z + wA.w)) + ((wB.x + wB.y) + (wB.z + wB.w));
        acc = fmaf(wA.x, v0, fmaf(wA.y, v1, fmaf(wA.z, v2, fmaf(wA.w, v3, acc))));
        acc = fmaf(wB.x, v4, fmaf(wB.y, v5, fmaf(wB.z, v6, fmaf(wB.w, v7, acc))));
    }
    h2[(size_t)n * F2 + lane] = acc / (den + EPS_F);
}

// ---------------- mean over nodes (fp64 accum) ----------------
#define MEAN_BLOCKS 256
__global__ __launch_bounds__(256) void k_mean(const float* __restrict__ h2,
                                              double* __restrict__ accum) {
    const int t = threadIdx.x;
    const int c = t & 63;
    double acc = 0.0;
    const size_t total = (size_t)N_NODES * F2;
    for (size_t idx = (size_t)blockIdx.x * 256 + t; idx < total; idx += (size_t)MEAN_BLOCKS * 256)
        acc += (double)h2[idx];
    __shared__ double red[256];
    red[t] = acc;
    __syncthreads();
    if (t < 64) {
        double v = red[t] + red[t + 64] + red[t + 128] + red[t + 192];
        atomicAdd(&accum[c], v);
    }
}

__global__ void k_final(const double* __restrict__ accum, const float* __restrict__ b2,
                        float* __restrict__ out) {
    int t = threadIdx.x;
    if (t < F2) out[t] = (float)(accum[t] * (1.0 / (double)N_NODES)) + b2[t];
}

// ---------------- launch ----------------
extern "C" void kernel_launch(void* const* d_in, const int* in_sizes, int n_in,
                              void* d_out, int out_size, void* d_ws, size_t ws_size,
                              hipStream_t stream) {
    (void)in_sizes; (void)n_in; (void)out_size; (void)ws_size;
    const float* x   = (const float*)d_in[0];
    const int*   ei  = (const int*)d_in[1];
    const float* W1  = (const float*)d_in[2];
    const float* as1 = (const float*)d_in[3];
    const float* ad1 = (const float*)d_in[4];
    const float* b1  = (const float*)d_in[5];
    const float* W2  = (const float*)d_in[6];
    const float* as2 = (const float*)d_in[7];
    const float* ad2 = (const float*)d_in[8];
    const float* b2  = (const float*)d_in[9];
    float* out = (float*)d_out;

    char* ws = (char*)d_ws;
    size_t off = 0;
    auto alloc = [&](size_t bytes) -> void* {
        void* p = ws + off;
        off += (bytes + 255) & ~(size_t)255;
        return p;
    };
    unsigned short* xw1bf = (unsigned short*)alloc((size_t)N_NODES * F1 * 2);
    float* h1       = (float*)alloc((size_t)N_NODES * F1 * 4);
    unsigned short* xw2bf = (unsigned short*)alloc((size_t)N_NODES * F2 * 2);
    float* h2       = (float*)alloc((size_t)N_NODES * F2 * 4);
    float* ew1      = (float*)alloc((size_t)H1 * TEP * 4);
    float* ew2      = (float*)alloc((size_t)TEP * 4);
    float* a1s      = (float*)alloc((size_t)N_NODES * H1 * 4);
    float* a1d      = (float*)alloc((size_t)N_NODES * H1 * 4);
    float* a2s      = (float*)alloc((size_t)N_NODES * 4);
    float* a2d      = (float*)alloc((size_t)N_NODES * 4);
    int*   deg      = (int*)alloc((size_t)N_NODES * 4);
    unsigned* cbuf  = (unsigned*)alloc((size_t)TE * 4);
    int*   cnt      = (int*)alloc((size_t)SCAN_TOT * 4);
    int*   bstart   = (int*)alloc((size_t)(NBINS + 1) * 4);
    int*   rowstart = (int*)alloc((size_t)(N_NODES + 1) * 4);
    int*   csr      = (int*)alloc((size_t)TEP * 4);
    int*   incl     = (int*)alloc((size_t)N_NODES * 4);
    int*   bsum     = (int*)alloc(64 * 4);
    double* accum   = (double*)alloc(F2 * 8);

    const int nscan = (N_NODES + 1023) / 1024;  // 49
    const int nwave4 = (N_NODES + 3) / 4;       // 12500

    hipMemsetAsync(accum, 0, F2 * 8, stream);
    k_l1_mm<<<N_NODES / 16, 256, 0, stream>>>(x, W1, as1, ad1, xw1bf, a1s, a1d);
    k_hist_coarse<<<NBLK_A, 256, 0, stream>>>(ei, cnt);
    k_cscan<<<1, 1024, 0, stream>>>(cnt, bstart);
    k_scatter_coarse<<<NBLK_A, 256, 0, stream>>>(ei, cnt, cbuf);
    k_fine_hist<<<NBINS, 256, 0, stream>>>(cbuf, bstart, deg);
    k_scan1<<<nscan, 1024, 0, stream>>>(deg, incl, bsum);
    k_scan2<<<1, 64, 0, stream>>>(bsum, nscan);
    k_scan3<<<nscan, 1024, 0, stream>>>(incl, bsum, rowstart);
    k_build_csr<<<NBINS, 256, 0, stream>>>(cbuf, bstart, rowstart, csr);
    k_ew1<<<nwave4, 256, 0, stream>>>(rowstart, csr, deg, a1s, a1d, ew1);
    k_l1_gather<<<nwave4, 256, 0, stream>>>(rowstart, csr, deg, ew1, xw1bf, b1, h1);
    k_l2_mm<<<N_NODES / 16, 256, 0, stream>>>(h1, W2, as2, ad2, xw2bf, a2s, a2d);
    k_ew2<<<nwave4, 256, 0, stream>>>(rowstart, csr, deg, a2s, a2d, ew2);
    k_l2_gather<<<nwave4, 256, 0, stream>>>(rowstart, csr, deg, ew2, xw2bf, h2);
    k_mean<<<MEAN_BLOCKS, 256, 0, stream>>>(h2, accum);
    k_final<<<1, 64, 0, stream>>>(accum, b2, out);
}

// Round 11
// 350.025 us; speedup vs baseline: 1.3449x; 1.1417x over previous
//
#include <hip/hip_runtime.h>
#include <math.h>

#define N_NODES 50000
#define E_RAW   1600000
#define TE      (E_RAW + N_NODES)     // 1650000 edges incl. self loops
#define TEP     (TE + 8 * N_NODES)    // CSR padded to 8-aligned rows (upper bound)
#define F_IN    128
#define H1      4
#define F1      128                   // H1*C1
#define F2      64
#define NEG_SLOPE 0.2f
#define EPS_F   1e-16f

// ---- bucket-sort CSR build params (all atomics are LDS-scope) ----
#define NBINS   196                   // coarse buckets: dst >> 8 (50000/256)
#define NBLK_A  128                   // blocks in coarse hist/scatter
#define EPB     ((TE + NBLK_A - 1) / NBLK_A)   // edges per block = 12891
#define MM_BLOCKS (N_NODES / 16)      // 3125

__device__ __forceinline__ float lrelu(float v) { return v > 0.f ? v : NEG_SLOPE * v; }

typedef float vf2 __attribute__((ext_vector_type(2)));

// bf16 round-to-nearest-even pack/unpack
__device__ __forceinline__ unsigned short f2bf(float f) {
    unsigned u = __float_as_uint(f);
    return (unsigned short)((u + 0x7fffu + ((u >> 16) & 1u)) >> 16);
}
__device__ __forceinline__ float bf2f(unsigned short s) {
    return __uint_as_float(((unsigned)s) << 16);
}
// fp8 OCP e4m3 via gfx950 HW cvt
__device__ __forceinline__ unsigned char f2fp8(float f) {
    int p = __builtin_amdgcn_cvt_pk_fp8_f32(f, f, 0, false);
    return (unsigned char)(p & 0xff);
}
__device__ __forceinline__ vf2 fp8pair2f(int u) {     // low 2 bytes -> 2 floats
    return __builtin_amdgcn_cvt_pk_f32_fp8(u, false);
}

// ---------------- layer1 matmul (+ fused coarse histogram) ----------------
// Blocks [0,3125): mm, 16 nodes/block, c=t&127, p=t>>7. xw stored fp8 e4m3;
// attention coefs fp32-exact from registers. #pragma unroll 2: VGPR cliff (r4).
// Blocks [3125, 3125+NBLK_A): coarse dst-histogram (independent work, overlaps).
__global__ __launch_bounds__(256) void k_l1_mm_hist(
    const float* __restrict__ x, const float* __restrict__ W,
    const float* __restrict__ atts, const float* __restrict__ attd,
    unsigned char* __restrict__ xwf8, float* __restrict__ a1s, float* __restrict__ a1d,
    const int* __restrict__ ei, int* __restrict__ cnt) {
    __shared__ float xs[16][F_IN];
    const int t = threadIdx.x;
    if (blockIdx.x >= MM_BLOCKS) {
        // ---- coarse histogram part (LDS atomics only) ----
        int* hist = (int*)&xs[0][0];
        const int blk = blockIdx.x - MM_BLOCKS;
        for (int i = t; i < NBINS; i += 256) hist[i] = 0;
        __syncthreads();
        const int e0 = blk * EPB, e1 = min(TE, e0 + EPB);
        for (int e = e0 + t; e < e1; e += 256) {
            int d = (e < E_RAW) ? ei[E_RAW + e] : (e - E_RAW);
            atomicAdd(&hist[d >> 8], 1);
        }
        __syncthreads();
        for (int i = t; i < NBINS; i += 256) cnt[i * NBLK_A + blk] = hist[i];
        return;
    }
    const int c = t & 127;
    const int p = t >> 7;
    const int n0 = blockIdx.x * 16;
    {
        const float4* src = (const float4*)(x + (size_t)n0 * F_IN);
        float4* dstv = (float4*)&xs[0][0];
        dstv[t] = src[t];
        dstv[t + 256] = src[t + 256];
    }
    __syncthreads();
    float acc[8];
#pragma unroll
    for (int j = 0; j < 8; ++j) acc[j] = 0.f;
    const float* xsp = &xs[p * 8][0];
#pragma unroll 2
    for (int k4 = 0; k4 < F_IN / 4; ++k4) {
        int k = k4 * 4;
        float w0 = W[(k + 0) * F1 + c];
        float w1 = W[(k + 1) * F1 + c];
        float w2 = W[(k + 2) * F1 + c];
        float w3 = W[(k + 3) * F1 + c];
#pragma unroll
        for (int j = 0; j < 8; ++j) {
            float4 xv = ((const float4*)(xsp + j * F_IN))[k4];
            acc[j] = fmaf(xv.x, w0, fmaf(xv.y, w1, fmaf(xv.z, w2, fmaf(xv.w, w3, acc[j]))));
        }
    }
    float ats = atts[c], atd = attd[c];
#pragma unroll
    for (int j = 0; j < 8; ++j) {
        int n = n0 + p * 8 + j;
        xwf8[(size_t)n * F1 + c] = f2fp8(acc[j]);
        float ps = acc[j] * ats, pd = acc[j] * atd;
#pragma unroll
        for (int off = 16; off; off >>= 1) {
            ps += __shfl_down(ps, off, 32);
            pd += __shfl_down(pd, off, 32);
        }
        if ((t & 31) == 0) {
            int h = (c >> 5);
            a1s[n * H1 + h] = ps;
            a1d[n * H1 + h] = pd;
        }
    }
}

// ---------------- per-bin scan of cnt across blocks + bin totals -------------
__global__ __launch_bounds__(64) void k_btot(int* __restrict__ cnt, int* __restrict__ btot) {
    const int bin = blockIdx.x, lane = threadIdx.x;
    int c0 = cnt[bin * NBLK_A + 2 * lane];
    int c1 = cnt[bin * NBLK_A + 2 * lane + 1];
    int s = c0 + c1;
    int incl = s;
#pragma unroll
    for (int off = 1; off < 64; off <<= 1) {
        int u = __shfl_up(incl, off, 64);
        if (lane >= off) incl += u;
    }
    int excl = incl - s;
    cnt[bin * NBLK_A + 2 * lane] = excl;
    cnt[bin * NBLK_A + 2 * lane + 1] = excl + c0;
    if (lane == 63) btot[bin] = incl;
}

// ---------------- exclusive scan of 196 bin totals -> bucket_start -----------
__global__ __launch_bounds__(64) void k_bstart(const int* __restrict__ btot,
                                               int* __restrict__ bstart) {
    const int lane = threadIdx.x;
    int v[4]; int s = 0;
#pragma unroll
    for (int j = 0; j < 4; ++j) {
        int i = 4 * lane + j;
        v[j] = (i < NBINS) ? btot[i] : 0;
        s += v[j];
    }
    int incl = s;
#pragma unroll
    for (int off = 1; off < 64; off <<= 1) {
        int u = __shfl_up(incl, off, 64);
        if (lane >= off) incl += u;
    }
    int run = incl - s;
#pragma unroll
    for (int j = 0; j < 4; ++j) {
        int i = 4 * lane + j;
        if (i < NBINS) bstart[i] = run;
        run += v[j];
    }
    if (lane == 63) bstart[NBINS] = TE;
}

// ---------------- scatter into coarse buckets (plain stores; r10 lesson) -----
// payload u32 = (dst&255)<<16 | src   (src < 65536)
__global__ __launch_bounds__(256) void k_scatter_coarse(const int* __restrict__ ei,
                                                        const int* __restrict__ cnt,
                                                        const int* __restrict__ bstart,
                                                        unsigned* __restrict__ cbuf) {
    __shared__ int cur[NBINS];
    const int t = threadIdx.x, blk = blockIdx.x;
    for (int i = t; i < NBINS; i += 256) cur[i] = cnt[i * NBLK_A + blk] + bstart[i];
    __syncthreads();
    const int e0 = blk * EPB, e1 = min(TE, e0 + EPB);
    for (int e = e0 + t; e < e1; e += 256) {
        int s, d;
        if (e < E_RAW) { s = ei[e]; d = ei[E_RAW + e]; }
        else { s = e - E_RAW; d = s; }
        int pos = atomicAdd(&cur[d >> 8], 1);   // LDS atomic
        cbuf[pos] = ((unsigned)(d & 255) << 16) | (unsigned)s;
    }
}

// ---------------- fine histogram -> deg --------------------
__global__ __launch_bounds__(256) void k_fine_hist(const unsigned* __restrict__ cbuf,
                                                   const int* __restrict__ bstart,
                                                   int* __restrict__ deg) {
    __shared__ int hist[256];
    const int t = threadIdx.x, b = blockIdx.x;
    hist[t] = 0;
    __syncthreads();
    const int i0 = bstart[b], i1 = bstart[b + 1];
    for (int i = i0 + t; i < i1; i += 256) atomicAdd(&hist[cbuf[i] >> 16], 1);
    __syncthreads();
    const int d = b * 256 + t;
    if (d < N_NODES) deg[d] = hist[t];
}

// ---------------- exclusive scan over 8-PADDED degrees (2-level) --------------
__global__ __launch_bounds__(1024) void k_scan1(const int* __restrict__ deg,
                                                int* __restrict__ incl, int* __restrict__ bsum) {
    int t = threadIdx.x, g = blockIdx.x;
    int idx = g * 1024 + t;
    int v = (idx < N_NODES) ? ((deg[idx] + 7) & ~7) : 0;
    int lane = t & 63, w = t >> 6;
#pragma unroll
    for (int off = 1; off < 64; off <<= 1) {
        int u = __shfl_up(v, off, 64);
        if (lane >= off) v += u;
    }
    __shared__ int ws[16];
    if (lane == 63) ws[w] = v;
    __syncthreads();
    if (w == 0 && lane < 16) {
        int s = ws[lane];
#pragma unroll
        for (int off = 1; off < 16; off <<= 1) {
            int u = __shfl_up(s, off, 16);
            if (lane >= off) s += u;
        }
        ws[lane] = s;
    }
    __syncthreads();
    if (w > 0) v += ws[w - 1];
    if (idx < N_NODES) incl[idx] = v;
    if (t == 1023) bsum[g] = v;
}

__global__ void k_scan2(int* __restrict__ bsum, int nblk) {
    int t = threadIdx.x;
    int v = (t < nblk) ? bsum[t] : 0;
#pragma unroll
    for (int off = 1; off < 64; off <<= 1) {
        int u = __shfl_up(v, off, 64);
        if (t >= off) v += u;
    }
    if (t < nblk) bsum[t] = v;
}

__global__ __launch_bounds__(1024) void k_scan3(const int* __restrict__ incl,
                                                const int* __restrict__ bsum,
                                                int* __restrict__ rowstart) {
    int idx = blockIdx.x * 1024 + threadIdx.x;
    if (idx >= N_NODES) return;
    int off = (blockIdx.x > 0) ? bsum[blockIdx.x - 1] : 0;
    rowstart[idx + 1] = incl[idx] + off;
    if (idx == 0) rowstart[0] = 0;
}

// ---------------- per-bucket scatter into csr (plain stores) -----------------
__global__ __launch_bounds__(256) void k_build_csr(const unsigned* __restrict__ cbuf,
                                                   const int* __restrict__ bstart,
                                                   const int* __restrict__ rowstart,
                                                   int* __restrict__ csr) {
    __shared__ int cur[256];
    const int t = threadIdx.x, b = blockIdx.x;
    const int d = b * 256 + t;
    cur[t] = (d < N_NODES) ? rowstart[d] : 0;
    __syncthreads();
    const int i0 = bstart[b], i1 = bstart[b + 1];
    for (int i = i0 + t; i < i1; i += 256) {
        unsigned v = cbuf[i];
        int pos = atomicAdd(&cur[v >> 16], 1);   // LDS atomic
        csr[pos] = (int)(v & 0xffffu);
    }
}

// ---------------- layer1 edge weights (bf16 planes) + pad zero-fill ----------
__global__ __launch_bounds__(256) void k_ew1(
    const int* __restrict__ rowstart, int* __restrict__ csr, const int* __restrict__ deg,
    const float* __restrict__ a1s, const float* __restrict__ a1d,
    unsigned short* __restrict__ ew1) {
    const int lane = threadIdx.x & 63;
    const int wid = threadIdx.x >> 6;
    const int n = blockIdx.x * 4 + wid;
    if (n >= N_NODES) return;
    const int rs = rowstart[n];
    const int dg = deg[n];
    const int re = rs + dg;
    const int re8 = rs + ((dg + 7) & ~7);
    const float4 ad = ((const float4*)a1d)[n];
    for (int i = rs + lane; i < re8; i += 64) {
        if (i < re) {
            int s = csr[i];
            float4 as = ((const float4*)a1s)[s];
            ew1[0 * TEP + i] = f2bf(expf(lrelu(as.x + ad.x)));
            ew1[1 * TEP + i] = f2bf(expf(lrelu(as.y + ad.y)));
            ew1[2 * TEP + i] = f2bf(expf(lrelu(as.z + ad.z)));
            ew1[3 * TEP + i] = f2bf(expf(lrelu(as.w + ad.w)));
        } else {
            csr[i] = 0;
            ew1[0 * TEP + i] = 0;
            ew1[1 * TEP + i] = 0;
            ew1[2 * TEP + i] = 0;
            ew1[3 * TEP + i] = 0;
        }
    }
}

// ---------------- layer1 gather: fp8 rows + bf16 weights, 8 edges/iter -------
__global__ __launch_bounds__(256) void k_l1_gather(
    const int* __restrict__ rowstart, const int* __restrict__ csr,
    const int* __restrict__ deg, const unsigned short* __restrict__ ew1,
    const unsigned short* __restrict__ xw8, const float* __restrict__ b1,
    float* __restrict__ h1) {
    const int lane = threadIdx.x & 63;
    const int wid = threadIdx.x >> 6;
    const int n = blockIdx.x * 4 + wid;
    if (n >= N_NODES) return;
    const int rs = rowstart[n];
    const int nb8 = (deg[n] + 7) >> 3;
    const int h = lane >> 4;
    const int4* c4 = (const int4*)(csr + rs);
    const ushort4* w4 = (const ushort4*)(ew1 + h * TEP + rs);
    float den = 0.f, ax = 0.f, ay = 0.f;
    for (int b = 0; b < nb8; ++b) {
        int4 sA = c4[2 * b], sB = c4[2 * b + 1];
        ushort4 wA = w4[2 * b], wB = w4[2 * b + 1];
        int u0 = xw8[sA.x * 64 + lane], u1 = xw8[sA.y * 64 + lane];
        int u2 = xw8[sA.z * 64 + lane], u3 = xw8[sA.w * 64 + lane];
        int u4 = xw8[sB.x * 64 + lane], u5 = xw8[sB.y * 64 + lane];
        int u6 = xw8[sB.z * 64 + lane], u7 = xw8[sB.w * 64 + lane];
        vf2 v0 = fp8pair2f(u0), v1 = fp8pair2f(u1), v2 = fp8pair2f(u2), v3 = fp8pair2f(u3);
        vf2 v4 = fp8pair2f(u4), v5 = fp8pair2f(u5), v6 = fp8pair2f(u6), v7 = fp8pair2f(u7);
        float wa0 = bf2f(wA.x), wa1 = bf2f(wA.y), wa2 = bf2f(wA.z), wa3 = bf2f(wA.w);
        float wb0 = bf2f(wB.x), wb1 = bf2f(wB.y), wb2 = bf2f(wB.z), wb3 = bf2f(wB.w);
        den += ((wa0 + wa1) + (wa2 + wa3)) + ((wb0 + wb1) + (wb2 + wb3));
        ax = fmaf(wa0, v0.x, fmaf(wa1, v1.x, fmaf(wa2, v2.x, fmaf(wa3, v3.x, ax))));
        ay = fmaf(wa0, v0.y, fmaf(wa1, v1.y, fmaf(wa2, v2.y, fmaf(wa3, v3.y, ay))));
        ax = fmaf(wb0, v4.x, fmaf(wb1, v5.x, fmaf(wb2, v6.x, fmaf(wb3, v7.x, ax))));
        ay = fmaf(wb0, v4.y, fmaf(wb1, v5.y, fmaf(wb2, v6.y, fmaf(wb3, v7.y, ay))));
    }
    const float inv = 1.f / (den + EPS_F);
    const int c0 = 2 * lane;
    float o0 = fmaf(ax, inv, b1[c0]);
    float o1 = fmaf(ay, inv, b1[c0 + 1]);
    o0 = o0 > 0.f ? o0 : expm1f(o0);
    o1 = o1 > 0.f ? o1 : expm1f(o1);
    ((float2*)h1)[(size_t)n * 64 + lane] = make_float2(o0, o1);
}

// ---------------- layer2 matmul + attention coefs (fp8 xw2) ------------------
__global__ __launch_bounds__(256) void k_l2_mm(
    const float* __restrict__ h1, const float* __restrict__ W,
    const float* __restrict__ atts, const float* __restrict__ attd,
    unsigned char* __restrict__ xwf8, float* __restrict__ a2s, float* __restrict__ a2d) {
    const int t = threadIdx.x;
    const int c = t & 63;
    const int p = t >> 6;
    const int n0 = blockIdx.x * 16;
    __shared__ float xs[16][F1];
    {
        const float4* src = (const float4*)(h1 + (size_t)n0 * F1);
        float4* dstv = (float4*)&xs[0][0];
        dstv[t] = src[t];
        dstv[t + 256] = src[t + 256];
    }
    __syncthreads();
    float acc[4];
#pragma unroll
    for (int j = 0; j < 4; ++j) acc[j] = 0.f;
    const float* xsp = &xs[p * 4][0];
#pragma unroll 2
    for (int k4 = 0; k4 < F1 / 4; ++k4) {
        int k = k4 * 4;
        float w0 = W[(k + 0) * F2 + c];
        float w1 = W[(k + 1) * F2 + c];
        float w2 = W[(k + 2) * F2 + c];
        float w3 = W[(k + 3) * F2 + c];
#pragma unroll
        for (int j = 0; j < 4; ++j) {
            float4 xv = ((const float4*)(xsp + j * F1))[k4];
            acc[j] = fmaf(xv.x, w0, fmaf(xv.y, w1, fmaf(xv.z, w2, fmaf(xv.w, w3, acc[j]))));
        }
    }
    float ats = atts[c], atd = attd[c];
#pragma unroll
    for (int j = 0; j < 4; ++j) {
        int n = n0 + p * 4 + j;
        xwf8[(size_t)n * F2 + c] = f2fp8(acc[j]);
        float ps = acc[j] * ats, pd = acc[j] * atd;
#pragma unroll
        for (int off = 32; off; off >>= 1) {
            ps += __shfl_down(ps, off, 64);
            pd += __shfl_down(pd, off, 64);
        }
        if (c == 0) { a2s[n] = ps; a2d[n] = pd; }
    }
}

// ---------------- layer2 edge weights (bf16) ----------------
__global__ __launch_bounds__(256) void k_ew2(
    const int* __restrict__ rowstart, const int* __restrict__ csr,
    const int* __restrict__ deg,
    const float* __restrict__ a2s, const float* __restrict__ a2d,
    unsigned short* __restrict__ ew2) {
    const int lane = threadIdx.x & 63;
    const int wid = threadIdx.x >> 6;
    const int n = blockIdx.x * 4 + wid;
    if (n >= N_NODES) return;
    const int rs = rowstart[n];
    const int dg = deg[n];
    const int re = rs + dg;
    const int re8 = rs + ((dg + 7) & ~7);
    const float adv = a2d[n];
    for (int i = rs + lane; i < re8; i += 64) {
        if (i < re) {
            int s = csr[i];
            ew2[i] = f2bf(expf(lrelu(a2s[s] + adv)));
        } else {
            ew2[i] = 0;
        }
    }
}

// ---------------- layer2 gather: fp8 rows + bf16 weights ---------------------
__global__ __launch_bounds__(256) void k_l2_gather(
    const int* __restrict__ rowstart, const int* __restrict__ csr,
    const int* __restrict__ deg, const unsigned short* __restrict__ ew2,
    const unsigned char* __restrict__ xw8, float* __restrict__ h2) {
    const int lane = threadIdx.x & 63;
    const int wid = threadIdx.x >> 6;
    const int n = blockIdx.x * 4 + wid;
    if (n >= N_NODES) return;
    const int rs = rowstart[n];
    const int nb8 = (deg[n] + 7) >> 3;
    const int4* c4 = (const int4*)(csr + rs);
    const ushort4* w4 = (const ushort4*)(ew2 + rs);
    float den = 0.f, acc = 0.f;
    for (int b = 0; b < nb8; ++b) {
        int4 sA = c4[2 * b], sB = c4[2 * b + 1];
        ushort4 wA = w4[2 * b], wB = w4[2 * b + 1];
        int u0 = xw8[(size_t)sA.x * F2 + lane], u1 = xw8[(size_t)sA.y * F2 + lane];
        int u2 = xw8[(size_t)sA.z * F2 + lane], u3 = xw8[(size_t)sA.w * F2 + lane];
        int u4 = xw8[(size_t)sB.x * F2 + lane], u5 = xw8[(size_t)sB.y * F2 + lane];
        int u6 = xw8[(size_t)sB.z * F2 + lane], u7 = xw8[(size_t)sB.w * F2 + lane];
        float v0 = fp8pair2f(u0).x, v1 = fp8pair2f(u1).x;
        float v2 = fp8pair2f(u2).x, v3 = fp8pair2f(u3).x;
        float v4 = fp8pair2f(u4).x, v5 = fp8pair2f(u5).x;
        float v6 = fp8pair2f(u6).x, v7 = fp8pair2f(u7).x;
        float wa0 = bf2f(wA.x), wa1 = bf2f(wA.y), wa2 = bf2f(wA.z), wa3 = bf2f(wA.w);
        float wb0 = bf2f(wB.x), wb1 = bf2f(wB.y), wb2 = bf2f(wB.z), wb3 = bf2f(wB.w);
        den += ((wa0 + wa1) + (wa2 + wa3)) + ((wb0 + wb1) + (wb2 + wb3));
        acc = fmaf(wa0, v0, fmaf(wa1, v1, fmaf(wa2, v2, fmaf(wa3, v3, acc))));
        acc = fmaf(wb0, v4, fmaf(wb1, v5, fmaf(wb2, v6, fmaf(wb3, v7, acc))));
    }
    h2[(size_t)n * F2 + lane] = acc / (den + EPS_F);
}

// ---------------- mean over nodes (fp64 accum) ----------------
#define MEAN_BLOCKS 256
__global__ __launch_bounds__(256) void k_mean(const float* __restrict__ h2,
                                              double* __restrict__ accum) {
    const int t = threadIdx.x;
    const int c = t & 63;
    double acc = 0.0;
    const size_t total = (size_t)N_NODES * F2;
    for (size_t idx = (size_t)blockIdx.x * 256 + t; idx < total; idx += (size_t)MEAN_BLOCKS * 256)
        acc += (double)h2[idx];
    __shared__ double red[256];
    red[t] = acc;
    __syncthreads();
    if (t < 64) {
        double v = red[t] + red[t + 64] + red[t + 128] + red[t + 192];
        atomicAdd(&accum[c], v);
    }
}

__global__ void k_final(const double* __restrict__ accum, const float* __restrict__ b2,
                        float* __restrict__ out) {
    int t = threadIdx.x;
    if (t < F2) out[t] = (float)(accum[t] * (1.0 / (double)N_NODES)) + b2[t];
}

// ---------------- launch ----------------
extern "C" void kernel_launch(void* const* d_in, const int* in_sizes, int n_in,
                              void* d_out, int out_size, void* d_ws, size_t ws_size,
                              hipStream_t stream) {
    (void)in_sizes; (void)n_in; (void)out_size; (void)ws_size;
    const float* x   = (const float*)d_in[0];
    const int*   ei  = (const int*)d_in[1];
    const float* W1  = (const float*)d_in[2];
    const float* as1 = (const float*)d_in[3];
    const float* ad1 = (const float*)d_in[4];
    const float* b1  = (const float*)d_in[5];
    const float* W2  = (const float*)d_in[6];
    const float* as2 = (const float*)d_in[7];
    const float* ad2 = (const float*)d_in[8];
    const float* b2  = (const float*)d_in[9];
    float* out = (float*)d_out;

    char* ws = (char*)d_ws;
    size_t off = 0;
    auto alloc = [&](size_t bytes) -> void* {
        void* p = ws + off;
        off += (bytes + 255) & ~(size_t)255;
        return p;
    };
    unsigned char*  xw1f8 = (unsigned char*)alloc((size_t)N_NODES * F1);
    float* h1       = (float*)alloc((size_t)N_NODES * F1 * 4);
    unsigned char*  xw2f8 = (unsigned char*)alloc((size_t)N_NODES * F2);
    float* h2       = (float*)alloc((size_t)N_NODES * F2 * 4);
    unsigned short* ew1 = (unsigned short*)alloc((size_t)H1 * TEP * 2);
    unsigned short* ew2 = (unsigned short*)alloc((size_t)TEP * 2);
    float* a1s      = (float*)alloc((size_t)N_NODES * H1 * 4);
    float* a1d      = (float*)alloc((size_t)N_NODES * H1 * 4);
    float* a2s      = (float*)alloc((size_t)N_NODES * 4);
    float* a2d      = (float*)alloc((size_t)N_NODES * 4);
    int*   deg      = (int*)alloc((size_t)N_NODES * 4);
    unsigned* cbuf  = (unsigned*)alloc((size_t)TE * 4);
    int*   cnt      = (int*)alloc((size_t)NBINS * NBLK_A * 4);
    int*   btot     = (int*)alloc((size_t)NBINS * 4);
    int*   bstart   = (int*)alloc((size_t)(NBINS + 1) * 4);
    int*   rowstart = (int*)alloc((size_t)(N_NODES + 1) * 4);
    int*   csr      = (int*)alloc((size_t)TEP * 4);
    int*   incl     = (int*)alloc((size_t)N_NODES * 4);
    int*   bsum     = (int*)alloc(64 * 4);
    double* accum   = (double*)alloc(F2 * 8);

    const int nscan = (N_NODES + 1023) / 1024;  // 49
    const int nwave4 = (N_NODES + 3) / 4;       // 12500

    hipMemsetAsync(accum, 0, F2 * 8, stream);
    k_l1_mm_hist<<<MM_BLOCKS + NBLK_A, 256, 0, stream>>>(x, W1, as1, ad1, xw1f8, a1s, a1d, ei, cnt);
    k_btot<<<NBINS, 64, 0, stream>>>(cnt, btot);
    k_bstart<<<1, 64, 0, stream>>>(btot, bstart);
    k_scatter_coarse<<<NBLK_A, 256, 0, stream>>>(ei, cnt, bstart, cbuf);
    k_fine_hist<<<NBINS, 256, 0, stream>>>(cbuf, bstart, deg);
    k_scan1<<<nscan, 1024, 0, stream>>>(deg, incl, bsum);
    k_scan2<<<1, 64, 0, stream>>>(bsum, nscan);
    k_scan3<<<nscan, 1024, 0, stream>>>(incl, bsum, rowstart);
    k_build_csr<<<NBINS, 256, 0, stream>>>(cbuf, bstart, rowstart, csr);
    k_ew1<<<nwave4, 256, 0, stream>>>(rowstart, csr, deg, a1s, a1d, ew1);
    k_l1_gather<<<nwave4, 256, 0, stream>>>(rowstart, csr, deg, ew1,
                                            (const unsigned short*)xw1f8, b1, h1);
    k_l2_mm<<<MM_BLOCKS, 256, 0, stream>>>(h1, W2, as2, ad2, xw2f8, a2s, a2d);
    k_ew2<<<nwave4, 256, 0, stream>>>(rowstart, csr, deg, a2s, a2d, ew2);
    k_l2_gather<<<nwave4, 256, 0, stream>>>(rowstart, csr, deg, ew2, xw2f8, h2);
    k_mean<<<MEAN_BLOCKS, 256, 0, stream>>>(h2, accum);
    k_final<<<1, 64, 0, stream>>>(accum, b2, out);
}